// Round 5
// baseline (123.483 us; speedup 1.0000x reference)
//
#include <hip/hip_runtime.h>
#include <hip/hip_bf16.h>

// HeteroLinear: out[b,n,o] = sum_i x[b,n,i] * W[t[n]][o][i] + bias[t[n]][o]
// B=16, N=16384, F_IN=F_OUT=128, NUM_TYPES=16, fp32 in/out.
//
// Round 5: (a) hl_main __launch_bounds__(512,8) — VGPR was 56, well under
// the 64 needed for 8 waves/EU, so the old (512,4) was a self-inflicted
// 50% occupancy cap (measured 33%). (b) prep fused 3->2 kernels: scatter
// blocks redundantly compute the deterministic prefix from the hist table.

#define NN 16384
#define FF 128
#define NT 16
#define NPB 8            // nodes per main block = waves per main block
#define NBLK (NN / NPB + NT)
#define PB 64            // prep blocks
#define WS_BH 16448      // ws offset of bh[t*PB + b] (after order array)

typedef __bf16 bf16x8 __attribute__((ext_vector_type(8)));
typedef float  f32x4  __attribute__((ext_vector_type(4)));

// ws int layout: [0:16) cnt, [16:32) off, [32:49) blkoff[0..16],
//                [64:64+NN) order, [WS_BH:WS_BH+NT*PB) per-block hist

__global__ __launch_bounds__(256) void hl_hist(const int* __restrict__ tv,
                                               int* __restrict__ ws) {
    __shared__ int wh[4][NT];
    const int tid = threadIdx.x, lane = tid & 63, wv = tid >> 6;
    const int t = tv[blockIdx.x * 256 + tid];
#pragma unroll
    for (int ty = 0; ty < NT; ++ty) {
        const unsigned long long m = __ballot(t == ty);
        if (lane == 0) wh[wv][ty] = __popcll(m);
    }
    __syncthreads();
    if (tid < NT)
        ws[WS_BH + tid * PB + blockIdx.x] = wh[0][tid] + wh[1][tid] + wh[2][tid] + wh[3][tid];
}

__global__ __launch_bounds__(256) void hl_scatter(const int* __restrict__ tv,
                                                  int* __restrict__ ws) {
    __shared__ int bh[NT * PB];
    __shared__ int scnt[NT], soff[NT], mybase[NT];
    __shared__ int wh[4][NT], wbase[4][NT];
    const int tid = threadIdx.x, lane = tid & 63, wv = tid >> 6;

    for (int i = tid; i < NT * PB; i += 256) bh[i] = ws[WS_BH + i];

    const int n = blockIdx.x * 256 + tid;
    const int t = tv[n];
    int myrank = 0;
#pragma unroll
    for (int ty = 0; ty < NT; ++ty) {
        const unsigned long long m = __ballot(t == ty);
        if (lane == 0) wh[wv][ty] = __popcll(m);
        if (t == ty) myrank = __popcll(m & ((1ull << lane) - 1ull));
    }
    __syncthreads();
    if (tid < NT) {                 // per-type: total count + prefix at my block
        int acc = 0, myb = 0;
        for (int b = 0; b < PB; ++b) {
            if (b == (int)blockIdx.x) myb = acc;
            acc += bh[tid * PB + b];
        }
        scnt[tid] = acc;
        mybase[tid] = myb;
    }
    __syncthreads();
    if (tid == 0) {
        int acc = 0, bacc = 0;
        for (int ty = 0; ty < NT; ++ty) {
            soff[ty] = acc;
            if (blockIdx.x == 0) {
                ws[ty]      = scnt[ty];
                ws[16 + ty] = acc;
                ws[32 + ty] = bacc;
            }
            acc  += scnt[ty];
            bacc += (scnt[ty] + NPB - 1) / NPB;
        }
        if (blockIdx.x == 0) ws[48] = bacc;
    }
    __syncthreads();
    if (tid < NT) {
        int base = soff[tid] + mybase[tid];
        for (int w = 0; w < 4; ++w) { wbase[w][tid] = base; base += wh[w][tid]; }
    }
    __syncthreads();
    ws[64 + wbase[wv][t] + myrank] = n;
}

__global__ __launch_bounds__(512, 8) void hl_main(
    const float* __restrict__ x,      // [16][NN][128]
    const float* __restrict__ W,      // [16][128][128]
    const float* __restrict__ bias,   // [16][128]
    const int*   __restrict__ ws,
    float*       __restrict__ out)    // [16][NN][128]
{
    const int lane = threadIdx.x & 63;
    const int wv   = threadIdx.x >> 6;   // 0..7 = node slot in chunk

    // block -> (type, chunk) via padded block offsets
    const int probe = (lane < 17) ? ws[32 + lane] : 0x7fffffff;
    const unsigned long long m = __ballot(lane < 17 && (int)blockIdx.x >= probe);
    const int t = __popcll(m) - 1;
    if (t >= NT) return;

    const int cnt   = ws[t];
    const int off   = ws[16 + t];
    const int chunk = blockIdx.x - ws[32 + t];
    const int start = chunk * NPB;
    const int nn    = min(NPB, cnt - start);
    const bool valid = (wv < nn);
    const int n = ws[64 + off + start + (valid ? wv : 0)];

    const int lrow = lane & 15;   // A row (b) / B col (o) / D col (o)
    const int lgrp = lane >> 4;   // k-group of 8 / D row-group

    // prefetch this wave's x tile before W staging (latency overlaps staging)
    const float* xp = x + (size_t)lrow * ((size_t)NN * FF) + (size_t)n * FF + lgrp * 8;
    f32x4 xv[8];
#pragma unroll
    for (int kk = 0; kk < 4; ++kk) {
        xv[2 * kk]     = *(const f32x4*)(xp + kk * 32);
        xv[2 * kk + 1] = *(const f32x4*)(xp + kk * 32 + 4);
    }

    // stage W[t] as bf16 [o][k], 256B/row, XOR-swizzled 16B slots
    __shared__ __align__(16) unsigned char Wl[FF * 256];
    const float* Wt = W + t * (FF * FF);
#pragma unroll
    for (int ii = 0; ii < 4; ++ii) {
        const int idx = ii * 512 + threadIdx.x;
        const float* p = Wt + idx * 8;
        f32x4 a = *(const f32x4*)p;
        f32x4 b = *(const f32x4*)(p + 4);
        bf16x8 v;
#pragma unroll
        for (int j = 0; j < 4; ++j) { v[j] = (__bf16)a[j]; v[4 + j] = (__bf16)b[j]; }
        const int o  = idx >> 4;
        const int cb = (idx & 15) << 4;
        *(bf16x8*)(Wl + o * 256 + (cb ^ ((o & 7) << 4))) = v;
    }
    __syncthreads();

    // split x into hi/lo bf16
    bf16x8 ahi[4], alo[4];
#pragma unroll
    for (int kk = 0; kk < 4; ++kk) {
#pragma unroll
        for (int j = 0; j < 4; ++j) {
            const float f0 = xv[2 * kk][j], f1 = xv[2 * kk + 1][j];
            const __bf16 h0 = (__bf16)f0, h1 = (__bf16)f1;
            ahi[kk][j]     = h0;  alo[kk][j]     = (__bf16)(f0 - (float)h0);
            ahi[kk][4 + j] = h1;  alo[kk][4 + j] = (__bf16)(f1 - (float)h1);
        }
    }

    f32x4 acc[8];
#pragma unroll
    for (int ot = 0; ot < 8; ++ot) acc[ot] = (f32x4){0.f, 0.f, 0.f, 0.f};

#pragma unroll
    for (int kk = 0; kk < 4; ++kk) {
#pragma unroll
        for (int ot = 0; ot < 8; ++ot) {
            const int o  = ot * 16 + lrow;
            const int cb = (kk * 64 + lgrp * 16) ^ ((o & 7) << 4);
            const bf16x8 wf = *(const bf16x8*)(Wl + o * 256 + cb);
            acc[ot] = __builtin_amdgcn_mfma_f32_16x16x32_bf16(ahi[kk], wf, acc[ot], 0, 0, 0);
            acc[ot] = __builtin_amdgcn_mfma_f32_16x16x32_bf16(alo[kk], wf, acc[ot], 0, 0, 0);
        }
    }

    if (valid) {
#pragma unroll
        for (int ot = 0; ot < 8; ++ot) {
            const int o  = ot * 16 + lrow;
            const float bv = bias[t * FF + o];
#pragma unroll
            for (int r = 0; r < 4; ++r) {
                out[(size_t)(lgrp * 4 + r) * ((size_t)NN * FF) + (size_t)n * FF + o]
                    = acc[ot][r] + bv;
            }
        }
    }
}

extern "C" void kernel_launch(void* const* d_in, const int* in_sizes, int n_in,
                              void* d_out, int out_size, void* d_ws, size_t ws_size,
                              hipStream_t stream) {
    const float* x    = (const float*)d_in[0];
    const int*   tv   = (const int*)d_in[1];
    const float* W    = (const float*)d_in[2];
    const float* bias = (const float*)d_in[3];
    float*       out  = (float*)d_out;
    int*         wsI  = (int*)d_ws;

    hl_hist<<<PB, 256, 0, stream>>>(tv, wsI);
    hl_scatter<<<PB, 256, 0, stream>>>(tv, wsI);
    hl_main<<<NBLK, 512, 0, stream>>>(x, W, bias, wsI, out);
}

// Round 6
// 77.257 us; speedup vs baseline: 1.5983x; 1.5983x over previous
//
#include <hip/hip_runtime.h>
#include <hip/hip_bf16.h>

// HeteroLinear: out[b,n,o] = sum_i x[b,n,i] * W[t[n]][o][i] + bias[t[n]][o]
// B=16, N=16384, F_IN=F_OUT=128, NUM_TYPES=16, fp32 in/out.
//
// Round 6: revert the (512,8) register strangle (R5: VGPR 56->32 forced,
// FETCH +35MB, 1.4x slower). Attack latency with per-wave software
// pipelining instead: 256 threads / 4 waves, NPB=16 -> 4 nodes per wave,
// serial loop with next-node x prefetch issued right after the current
// node's f32->bf16 convert frees the xv registers. W staged once per 16
// nodes. launch_bounds(256,4): cap 128 VGPR, natural ~110, no forcing.

#define NN 16384
#define FF 128
#define NT 16
#define NPB 16           // nodes per main block (4 waves x 4 nodes serial)
#define NBLK (NN / NPB + NT)
#define PB 64            // prep blocks
#define WS_BH 16448      // ws offset of bh[t*PB + b] (after order array)

typedef __bf16 bf16x8 __attribute__((ext_vector_type(8)));
typedef float  f32x4  __attribute__((ext_vector_type(4)));

// ws int layout: [0:16) cnt, [16:32) off, [32:49) blkoff[0..16],
//                [64:64+NN) order, [WS_BH:WS_BH+NT*PB) per-block hist

__global__ __launch_bounds__(256) void hl_hist(const int* __restrict__ tv,
                                               int* __restrict__ ws) {
    __shared__ int wh[4][NT];
    const int tid = threadIdx.x, lane = tid & 63, wv = tid >> 6;
    const int t = tv[blockIdx.x * 256 + tid];
#pragma unroll
    for (int ty = 0; ty < NT; ++ty) {
        const unsigned long long m = __ballot(t == ty);
        if (lane == 0) wh[wv][ty] = __popcll(m);
    }
    __syncthreads();
    if (tid < NT)
        ws[WS_BH + tid * PB + blockIdx.x] = wh[0][tid] + wh[1][tid] + wh[2][tid] + wh[3][tid];
}

__global__ __launch_bounds__(256) void hl_scatter(const int* __restrict__ tv,
                                                  int* __restrict__ ws) {
    __shared__ int bh[NT * PB];
    __shared__ int scnt[NT], soff[NT], mybase[NT];
    __shared__ int wh[4][NT], wbase[4][NT];
    const int tid = threadIdx.x, lane = tid & 63, wv = tid >> 6;

    for (int i = tid; i < NT * PB; i += 256) bh[i] = ws[WS_BH + i];

    const int n = blockIdx.x * 256 + tid;
    const int t = tv[n];
    int myrank = 0;
#pragma unroll
    for (int ty = 0; ty < NT; ++ty) {
        const unsigned long long m = __ballot(t == ty);
        if (lane == 0) wh[wv][ty] = __popcll(m);
        if (t == ty) myrank = __popcll(m & ((1ull << lane) - 1ull));
    }
    __syncthreads();
    if (tid < NT) {                 // per-type: total count + prefix at my block
        int acc = 0, myb = 0;
        for (int b = 0; b < PB; ++b) {
            if (b == (int)blockIdx.x) myb = acc;
            acc += bh[tid * PB + b];
        }
        scnt[tid] = acc;
        mybase[tid] = myb;
    }
    __syncthreads();
    if (tid == 0) {
        int acc = 0, bacc = 0;
        for (int ty = 0; ty < NT; ++ty) {
            soff[ty] = acc;
            if (blockIdx.x == 0) {
                ws[ty]      = scnt[ty];
                ws[16 + ty] = acc;
                ws[32 + ty] = bacc;
            }
            acc  += scnt[ty];
            bacc += (scnt[ty] + NPB - 1) / NPB;
        }
        if (blockIdx.x == 0) ws[48] = bacc;
    }
    __syncthreads();
    if (tid < NT) {
        int base = soff[tid] + mybase[tid];
        for (int w = 0; w < 4; ++w) { wbase[w][tid] = base; base += wh[w][tid]; }
    }
    __syncthreads();
    ws[64 + wbase[wv][t] + myrank] = n;
}

__global__ __launch_bounds__(256, 4) void hl_main(
    const float* __restrict__ x,      // [16][NN][128]
    const float* __restrict__ W,      // [16][128][128]
    const float* __restrict__ bias,   // [16][128]
    const int*   __restrict__ ws,
    float*       __restrict__ out)    // [16][NN][128]
{
    const int lane = threadIdx.x & 63;
    const int wv   = threadIdx.x >> 6;   // 0..3

    // block -> (type, chunk) via padded block offsets
    const int probe = (lane < 17) ? ws[32 + lane] : 0x7fffffff;
    const unsigned long long m = __ballot(lane < 17 && (int)blockIdx.x >= probe);
    const int t = __popcll(m) - 1;
    if (t >= NT) return;

    const int cnt   = ws[t];
    const int off   = ws[16 + t];
    const int chunk = blockIdx.x - ws[32 + t];
    const int start = chunk * NPB;
    const int nn    = min(NPB, cnt - start);

    const int lrow = lane & 15;   // A row (b) / B col (o) / D col (o)
    const int lgrp = lane >> 4;   // k-group of 8 / D row-group

    // this wave's 4 nodes (contiguous slice of the chunk)
    int  nd[4];
    bool vld[4];
#pragma unroll
    for (int i = 0; i < 4; ++i) {
        const int j = wv * 4 + i;
        vld[i] = (j < nn);
        nd[i]  = ws[64 + off + start + (vld[i] ? j : 0)];
    }

    const float* xbase = x + (size_t)lrow * ((size_t)NN * FF) + lgrp * 8;

    // issue node-0 x loads before W staging (latency under staging)
    f32x4 xv[8];
#pragma unroll
    for (int kk = 0; kk < 4; ++kk) {
        const float* xp = xbase + (size_t)nd[0] * FF + kk * 32;
        xv[2 * kk]     = *(const f32x4*)xp;
        xv[2 * kk + 1] = *(const f32x4*)(xp + 4);
    }

    // stage W[t] as bf16 [o][k], 256B/row, XOR-swizzled 16B slots
    __shared__ __align__(16) unsigned char Wl[FF * 256];
    const float* Wt = W + t * (FF * FF);
#pragma unroll
    for (int ii = 0; ii < 8; ++ii) {
        const int idx = ii * 256 + threadIdx.x;
        const float* p = Wt + idx * 8;
        f32x4 a = *(const f32x4*)p;
        f32x4 b = *(const f32x4*)(p + 4);
        bf16x8 v;
#pragma unroll
        for (int j = 0; j < 4; ++j) { v[j] = (__bf16)a[j]; v[4 + j] = (__bf16)b[j]; }
        const int o  = idx >> 4;
        const int cb = (idx & 15) << 4;
        *(bf16x8*)(Wl + o * 256 + (cb ^ ((o & 7) << 4))) = v;
    }

    float bv[8];
#pragma unroll
    for (int ot = 0; ot < 8; ++ot) bv[ot] = bias[t * FF + ot * 16 + lrow];

    __syncthreads();

#pragma unroll
    for (int i = 0; i < 4; ++i) {
        // convert current node's x to hi/lo bf16 (waits on its loads, frees xv)
        bf16x8 ahi[4], alo[4];
#pragma unroll
        for (int kk = 0; kk < 4; ++kk) {
#pragma unroll
            for (int j = 0; j < 4; ++j) {
                const float f0 = xv[2 * kk][j], f1 = xv[2 * kk + 1][j];
                const __bf16 h0 = (__bf16)f0, h1 = (__bf16)f1;
                ahi[kk][j]     = h0;  alo[kk][j]     = (__bf16)(f0 - (float)h0);
                ahi[kk][4 + j] = h1;  alo[kk][4 + j] = (__bf16)(f1 - (float)h1);
            }
        }

        // prefetch next node's x into the freed xv regs; in flight during MFMA
        if (i < 3) {
#pragma unroll
            for (int kk = 0; kk < 4; ++kk) {
                const float* xp = xbase + (size_t)nd[i + 1] * FF + kk * 32;
                xv[2 * kk]     = *(const f32x4*)xp;
                xv[2 * kk + 1] = *(const f32x4*)(xp + 4);
            }
        }

        f32x4 acc[8];
#pragma unroll
        for (int ot = 0; ot < 8; ++ot) acc[ot] = (f32x4){0.f, 0.f, 0.f, 0.f};

#pragma unroll
        for (int kk = 0; kk < 4; ++kk) {
#pragma unroll
            for (int ot = 0; ot < 8; ++ot) {
                const int o  = ot * 16 + lrow;
                const int cb = (kk * 64 + lgrp * 16) ^ ((o & 7) << 4);
                const bf16x8 wf = *(const bf16x8*)(Wl + o * 256 + cb);
                acc[ot] = __builtin_amdgcn_mfma_f32_16x16x32_bf16(ahi[kk], wf, acc[ot], 0, 0, 0);
                acc[ot] = __builtin_amdgcn_mfma_f32_16x16x32_bf16(alo[kk], wf, acc[ot], 0, 0, 0);
            }
        }

        if (vld[i]) {
            const int n = nd[i];
#pragma unroll
            for (int ot = 0; ot < 8; ++ot) {
                const int o = ot * 16 + lrow;
#pragma unroll
                for (int r = 0; r < 4; ++r) {
                    out[(size_t)(lgrp * 4 + r) * ((size_t)NN * FF) + (size_t)n * FF + o]
                        = acc[ot][r] + bv[ot];
                }
            }
        }
    }
}

extern "C" void kernel_launch(void* const* d_in, const int* in_sizes, int n_in,
                              void* d_out, int out_size, void* d_ws, size_t ws_size,
                              hipStream_t stream) {
    const float* x    = (const float*)d_in[0];
    const int*   tv   = (const int*)d_in[1];
    const float* W    = (const float*)d_in[2];
    const float* bias = (const float*)d_in[3];
    float*       out  = (float*)d_out;
    int*         wsI  = (int*)d_ws;

    hl_hist<<<PB, 256, 0, stream>>>(tv, wsI);
    hl_scatter<<<PB, 256, 0, stream>>>(tv, wsI);
    hl_main<<<NBLK, 256, 0, stream>>>(x, W, bias, wsI, out);
}